// Round 5
// baseline (825.504 us; speedup 1.0000x reference)
//
#include <hip/hip_runtime.h>
#include <hip/hip_bf16.h>

#define D 128            // EMBED_DIM
#define G 3              // NUM_GROUPS
#define BN 128           // dst nodes per bucket
#define CH 8192          // edges per bin block

// ---------------------------------------------------------------------------
// Kernel 1: per-node linear(128->3) + softmax -> coeff[n] (float4, w=0)
// Also emits a bf16 copy of X for the gather phase (halves gather traffic).
// ---------------------------------------------------------------------------
__global__ void lg_coeff_kernel(const float* __restrict__ X,
                                const float* __restrict__ W,
                                const float* __restrict__ b,
                                float4* __restrict__ coeff,
                                __hip_bfloat16* __restrict__ Xh,   // may be null
                                int n) {
    int node = (int)((blockIdx.x * (size_t)blockDim.x + threadIdx.x) >> 6);
    int lane = threadIdx.x & 63;
    if (node >= n) return;
    float2 x = ((const float2*)(X + (size_t)node * D))[lane];
    if (Xh) {
        __hip_bfloat162 h;
        h.x = __float2bfloat16(x.x);
        h.y = __float2bfloat16(x.y);
        ((__hip_bfloat162*)(Xh + (size_t)node * D))[lane] = h;
    }
    int d0 = lane * 2;
    float s0 = x.x * W[d0 * G + 0] + x.y * W[(d0 + 1) * G + 0];
    float s1 = x.x * W[d0 * G + 1] + x.y * W[(d0 + 1) * G + 1];
    float s2 = x.x * W[d0 * G + 2] + x.y * W[(d0 + 1) * G + 2];
    #pragma unroll
    for (int off = 32; off; off >>= 1) {
        s0 += __shfl_xor(s0, off);
        s1 += __shfl_xor(s1, off);
        s2 += __shfl_xor(s2, off);
    }
    s0 += b[0]; s1 += b[1]; s2 += b[2];     // T = 1.0
    float m = fmaxf(s0, fmaxf(s1, s2));
    float e0 = __expf(s0 - m), e1 = __expf(s1 - m), e2 = __expf(s2 - m);
    float inv = 1.0f / (e0 + e1 + e2);
    if (lane == 0) coeff[node] = make_float4(e0 * inv, e1 * inv, e2 * inv, 0.0f);
}

// ---------------------------------------------------------------------------
// Kernel 2: degree histogram (int atomics)
// ---------------------------------------------------------------------------
__global__ void lg_deg_kernel(const int* __restrict__ dst, int* __restrict__ deg, int E) {
    int e = (int)(blockIdx.x * (size_t)blockDim.x + threadIdx.x);
    if (e < E) atomicAdd(&deg[dst[e]], 1);
}

// ---------------------------------------------------------------------------
// Kernel 3a: block-level exclusive scan (coalesced), per-block totals.
// ---------------------------------------------------------------------------
__global__ void lg_scan_a_kernel(const int* __restrict__ deg, int* __restrict__ off,
                                 int* __restrict__ bsum, int n, int E) {
    __shared__ int lds[256];
    int tid = threadIdx.x;
    int t = blockIdx.x * 256 + tid;
    int v = (t < n) ? deg[t] : 0;
    lds[tid] = v;
    __syncthreads();
    #pragma unroll
    for (int d = 1; d < 256; d <<= 1) {
        int y = (tid >= d) ? lds[tid - d] : 0;
        __syncthreads();
        lds[tid] += y;
        __syncthreads();
    }
    if (t < n) off[t] = lds[tid] - v;            // exclusive within block
    if (tid == 255) bsum[blockIdx.x] = lds[255]; // block total
    if (t == 0) off[n] = E;                      // grand total known a priori
}

// ---------------------------------------------------------------------------
// Kernel 3b: add prefix of block sums; also init bucket write cursors
// cursor[bk] = off[bk*BN]  (exact bucket CSR-region base -> no overflow).
// ---------------------------------------------------------------------------
__global__ void lg_scan_b_kernel(int* __restrict__ off, const int* __restrict__ bsum,
                                 int* __restrict__ cursor, int n) {
    int b = blockIdx.x;
    int tid = threadIdx.x;
    int s = 0;
    for (int i = tid; i < b; i += 256) s += bsum[i];
    #pragma unroll
    for (int o = 32; o; o >>= 1) s += __shfl_xor(s, o);
    __shared__ int wsm[4];
    if ((tid & 63) == 0) wsm[tid >> 6] = s;
    __syncthreads();
    int S = wsm[0] + wsm[1] + wsm[2] + wsm[3];
    int t = b * 256 + tid;
    if (t < n) {
        int val = off[t] + S;
        off[t] = val;
        if ((tid & (BN - 1)) == 0) cursor[t / BN] = val;
    }
}

// ---------------------------------------------------------------------------
// Kernel 4: LDS-staged bucket binning. rec(u32) = src(16) | dst_low7 << 16.
// Per block: histogram -> scan -> LDS scatter -> bulk-reserve -> coalesced
// burst writes into exact bucket regions. Requires n <= 65536.
// ---------------------------------------------------------------------------
__global__ __launch_bounds__(256) void lg_bin_kernel(
        const int* __restrict__ src, const int* __restrict__ dst,
        int* __restrict__ cursor, unsigned int* __restrict__ temp,
        int E, int nbuck) {
    __shared__ unsigned int stage[CH];                     // 32 KB
    __shared__ int hist[512], sc[512], hbase[512], hcnt[512], gbs[512];
    int tid = threadIdx.x;
    int e0 = blockIdx.x * CH;
    int ecnt = min(CH, E - e0);
    for (int i = tid; i < 512; i += 256) { hist[i] = 0; hcnt[i] = 0; }
    __syncthreads();
    // pass 1: histogram
    for (int k = tid; k < ecnt; k += 256) {
        int d = dst[e0 + k];
        atomicAdd(&hist[d >> 7], 1);
    }
    __syncthreads();
    // inclusive scan over 512 entries (2 per thread)
    int i0 = tid, i1 = tid + 256;
    sc[i0] = hist[i0]; sc[i1] = hist[i1];
    __syncthreads();
    #pragma unroll
    for (int d = 1; d < 512; d <<= 1) {
        int v0 = (i0 >= d) ? sc[i0 - d] : 0;
        int v1 = (i1 >= d) ? sc[i1 - d] : 0;
        __syncthreads();
        sc[i0] += v0; sc[i1] += v1;
        __syncthreads();
    }
    hbase[i0] = sc[i0] - hist[i0];
    hbase[i1] = sc[i1] - hist[i1];
    __syncthreads();
    // pass 2: scatter into stage (src/dst re-read: L2-hot)
    for (int k = tid; k < ecnt; k += 256) {
        int s = src[e0 + k], d = dst[e0 + k];
        int bk = d >> 7;
        int idx = hbase[bk] + atomicAdd(&hcnt[bk], 1);
        stage[idx] = ((unsigned int)s & 0xFFFFu) | (((unsigned int)d & 127u) << 16);
    }
    // bulk-reserve global ranges (one atomic per non-empty bucket)
    for (int i = tid; i < nbuck; i += 256) {
        int c = hist[i];
        gbs[i] = c ? atomicAdd(&cursor[i], c) : 0;
    }
    __syncthreads();
    // coalesced burst flush: one wave per bucket round-robin
    int wv = tid >> 6, ln = tid & 63;
    for (int bk = wv; bk < nbuck; bk += 4) {
        int c = hist[bk];
        if (!c) continue;
        int gb = gbs[bk], hb = hbase[bk];
        for (int j = ln; j < c; j += 64) temp[gb + j] = stage[hb + j];
    }
}

// ---------------------------------------------------------------------------
// Kernel 5: bucket aggregation. One 512-thread block per 128-node bucket.
// LDS f32 accumulator acc[BN][128] (dynamic, 64KB) + cdl (dst coeffs).
// Streams bucket records; w = dot3(coeff[src], coeff[dst]) in f32;
// accumulates w * Xh[src,:] via LDS float atomics; epilogue scales by 1/deg.
// ---------------------------------------------------------------------------
__global__ __launch_bounds__(512) void lg_bucketagg_kernel(
        const __hip_bfloat16* __restrict__ Xh,
        const float4* __restrict__ coeff,
        const unsigned int* __restrict__ temp,
        const int* __restrict__ off,
        const int* __restrict__ deg,
        float* __restrict__ out, int n) {
    extern __shared__ float smem[];
    float*  acc = smem;                    // BN*128 floats = 64 KB
    float4* cdl = (float4*)(smem + BN * D);
    int b = blockIdx.x;
    int nb0 = b * BN;
    int tid = threadIdx.x;
    int wv = tid >> 6, ln = tid & 63;
    for (int i = tid; i < BN * D; i += 512) acc[i] = 0.0f;
    for (int i = tid; i < BN; i += 512)
        cdl[i] = (nb0 + i < n) ? coeff[nb0 + i] : make_float4(0, 0, 0, 0);
    __syncthreads();
    int rbeg = off[nb0];
    int rend = off[min(nb0 + BN, n)];
    for (int base = rbeg + wv * 64; base < rend; base += 8 * 64) {
        int cnt = min(rend - base, 64);
        unsigned int my = (ln < cnt) ? temp[base + ln] : 0u;
        int j = 0;
        for (; j + 3 < cnt; j += 4) {
            unsigned int r0 = __shfl(my, j + 0), r1 = __shfl(my, j + 1);
            unsigned int r2 = __shfl(my, j + 2), r3 = __shfl(my, j + 3);
            int s0 = (int)(r0 & 0xFFFFu), s1 = (int)(r1 & 0xFFFFu);
            int s2 = (int)(r2 & 0xFFFFu), s3 = (int)(r3 & 0xFFFFu);
            int d0 = (int)(r0 >> 16), d1 = (int)(r1 >> 16);
            int d2 = (int)(r2 >> 16), d3 = (int)(r3 >> 16);
            float4 c0 = coeff[s0], c1 = coeff[s1], c2 = coeff[s2], c3 = coeff[s3];
            __hip_bfloat162 h0 = ((const __hip_bfloat162*)(Xh + (size_t)s0 * D))[ln];
            __hip_bfloat162 h1 = ((const __hip_bfloat162*)(Xh + (size_t)s1 * D))[ln];
            __hip_bfloat162 h2 = ((const __hip_bfloat162*)(Xh + (size_t)s2 * D))[ln];
            __hip_bfloat162 h3 = ((const __hip_bfloat162*)(Xh + (size_t)s3 * D))[ln];
            float4 e0 = cdl[d0], e1 = cdl[d1], e2 = cdl[d2], e3 = cdl[d3];
            float w0 = c0.x * e0.x + c0.y * e0.y + c0.z * e0.z;
            float w1 = c1.x * e1.x + c1.y * e1.y + c1.z * e1.z;
            float w2 = c2.x * e2.x + c2.y * e2.y + c2.z * e2.z;
            float w3 = c3.x * e3.x + c3.y * e3.y + c3.z * e3.z;
            atomicAdd(&acc[d0 * D + 2 * ln + 0], w0 * __bfloat162float(h0.x));
            atomicAdd(&acc[d0 * D + 2 * ln + 1], w0 * __bfloat162float(h0.y));
            atomicAdd(&acc[d1 * D + 2 * ln + 0], w1 * __bfloat162float(h1.x));
            atomicAdd(&acc[d1 * D + 2 * ln + 1], w1 * __bfloat162float(h1.y));
            atomicAdd(&acc[d2 * D + 2 * ln + 0], w2 * __bfloat162float(h2.x));
            atomicAdd(&acc[d2 * D + 2 * ln + 1], w2 * __bfloat162float(h2.y));
            atomicAdd(&acc[d3 * D + 2 * ln + 0], w3 * __bfloat162float(h3.x));
            atomicAdd(&acc[d3 * D + 2 * ln + 1], w3 * __bfloat162float(h3.y));
        }
        for (; j < cnt; ++j) {
            unsigned int r0 = __shfl(my, j);
            int s0 = (int)(r0 & 0xFFFFu);
            int d0 = (int)(r0 >> 16);
            float4 c0 = coeff[s0];
            float4 e0 = cdl[d0];
            float w0 = c0.x * e0.x + c0.y * e0.y + c0.z * e0.z;
            __hip_bfloat162 h0 = ((const __hip_bfloat162*)(Xh + (size_t)s0 * D))[ln];
            atomicAdd(&acc[d0 * D + 2 * ln + 0], w0 * __bfloat162float(h0.x));
            atomicAdd(&acc[d0 * D + 2 * ln + 1], w0 * __bfloat162float(h0.y));
        }
    }
    __syncthreads();
    // epilogue: scale by 1/max(deg,1), coalesced write
    for (int idx = tid; idx < BN * 64; idx += 512) {
        int node = idx >> 6, l = idx & 63;
        int gn = nb0 + node;
        if (gn >= n) break;
        float invd = 1.0f / fmaxf((float)deg[gn], 1.0f);
        float2 r = make_float2(acc[node * D + 2 * l] * invd,
                               acc[node * D + 2 * l + 1] * invd);
        *(float2*)(out + (size_t)gn * D + 2 * l) = r;
    }
}

// ---------------------------------------------------------------------------
// Minimal-workspace / large-n fallback: float-atomic scatter
// ---------------------------------------------------------------------------
__global__ void lg_scatter_kernel(const float* __restrict__ X,
                                  const float4* __restrict__ coeff,
                                  const int* __restrict__ src, const int* __restrict__ dst,
                                  float* __restrict__ out, int E) {
    int e = (int)((blockIdx.x * (size_t)blockDim.x + threadIdx.x) >> 6);
    int lane = threadIdx.x & 63;
    if (e >= E) return;
    int s = src[e], d = dst[e];
    float4 cs = coeff[s], cd = coeff[d];
    float se = cs.x * cd.x + cs.y * cd.y + cs.z * cd.z;
    float2 x = ((const float2*)(X + (size_t)s * D))[lane];
    atomicAdd(&out[(size_t)d * D + lane * 2 + 0], se * x.x);
    atomicAdd(&out[(size_t)d * D + lane * 2 + 1], se * x.y);
}

__global__ void lg_scale_kernel(float* __restrict__ out, const int* __restrict__ deg, int n) {
    int node = (int)((blockIdx.x * (size_t)blockDim.x + threadIdx.x) >> 6);
    int lane = threadIdx.x & 63;
    if (node >= n) return;
    float invd = 1.0f / fmaxf((float)deg[node], 1.0f);
    float2* p = (float2*)(out + (size_t)node * D);
    float2 v = p[lane];
    p[lane] = make_float2(v.x * invd, v.y * invd);
}

extern "C" void kernel_launch(void* const* d_in, const int* in_sizes, int n_in,
                              void* d_out, int out_size, void* d_ws, size_t ws_size,
                              hipStream_t stream) {
    const float* X   = (const float*)d_in[0];
    const int*   src = (const int*)d_in[1];
    const int*   dst = (const int*)d_in[2];
    const float* W   = (const float*)d_in[3];
    const float* b   = (const float*)d_in[4];
    float* out = (float*)d_out;
    int n = in_sizes[0] / D;
    int E = in_sizes[1];

    int nb    = (n + 255) / 256;        // scan blocks
    int nbuck = (n + BN - 1) / BN;      // dst buckets

    char* ws = (char*)d_ws;
    size_t p = 0;
    auto alloc = [&](size_t bytes) -> void* {
        void* r = ws + p;
        p = (p + bytes + 255) & ~(size_t)255;
        return r;
    };
    float4* coeff  = (float4*)alloc((size_t)n * sizeof(float4));
    int*    deg    = (int*)alloc((size_t)n * sizeof(int));
    int*    off    = (int*)alloc((size_t)(n + 1) * sizeof(int));
    int*    bsum   = (int*)alloc((size_t)nb * sizeof(int));
    int*    cursor = (int*)alloc((size_t)nbuck * sizeof(int));
    unsigned int* temp = (unsigned int*)alloc((size_t)E * sizeof(unsigned int));
    __hip_bfloat16* Xh = (__hip_bfloat16*)alloc((size_t)n * D * sizeof(__hip_bfloat16));
    size_t p_full = p;

    int node_blocks = (n + 3) / 4;      // 4 waves (nodes) per 256-thread block
    int edge_blocks = (E + 255) / 256;
    int bin_blocks  = (E + CH - 1) / CH;

    bool fast_ok = (n <= 65536) && (nbuck <= 512) && (p_full <= ws_size);
    if (fast_ok) {
        hipMemsetAsync(deg, 0, (size_t)n * sizeof(int), stream);
        lg_coeff_kernel<<<node_blocks, 256, 0, stream>>>(X, W, b, coeff, Xh, n);
        lg_deg_kernel<<<edge_blocks, 256, 0, stream>>>(dst, deg, E);
        lg_scan_a_kernel<<<nb, 256, 0, stream>>>(deg, off, bsum, n, E);
        lg_scan_b_kernel<<<nb, 256, 0, stream>>>(off, bsum, cursor, n);
        lg_bin_kernel<<<bin_blocks, 256, 0, stream>>>(src, dst, cursor, temp, E, nbuck);
        size_t shmem = (size_t)BN * D * sizeof(float) + (size_t)BN * sizeof(float4);
        lg_bucketagg_kernel<<<nbuck, 512, shmem, stream>>>(Xh, coeff, temp, off, deg, out, n);
    } else {
        // fallback (~1 MB): coeff + deg; atomic scatter
        hipMemsetAsync(deg, 0, (size_t)n * sizeof(int), stream);
        hipMemsetAsync(out, 0, (size_t)n * D * sizeof(float), stream);
        lg_coeff_kernel<<<node_blocks, 256, 0, stream>>>(X, W, b, coeff, nullptr, n);
        lg_deg_kernel<<<edge_blocks, 256, 0, stream>>>(dst, deg, E);
        lg_scatter_kernel<<<(E + 3) / 4, 256, 0, stream>>>(X, coeff, src, dst, out, E);
        lg_scale_kernel<<<node_blocks, 256, 0, stream>>>(out, deg, n);
    }
}

// Round 6
// 136.178 us; speedup vs baseline: 6.0620x; 6.0620x over previous
//
#include <hip/hip_runtime.h>
#include <hip/hip_bf16.h>

#define D 128            // EMBED_DIM
#define G 3              // NUM_GROUPS
#define BN 128           // dst nodes per bucket (7 bits in record)
#define CH 8192          // edges per bin block
#define CAP 4096         // max records staged per bucket in sortagg (mean 2048)

// ---------------------------------------------------------------------------
// Kernel 1: per-node linear(128->3) + softmax -> coeff[n] (float4, w=0)
// Also emits a bf16 copy of X for the gather phase (halves gather traffic).
// ---------------------------------------------------------------------------
__global__ void lg_coeff_kernel(const float* __restrict__ X,
                                const float* __restrict__ W,
                                const float* __restrict__ b,
                                float4* __restrict__ coeff,
                                __hip_bfloat16* __restrict__ Xh,   // may be null
                                int n) {
    int node = (int)((blockIdx.x * (size_t)blockDim.x + threadIdx.x) >> 6);
    int lane = threadIdx.x & 63;
    if (node >= n) return;
    float2 x = ((const float2*)(X + (size_t)node * D))[lane];
    if (Xh) {
        __hip_bfloat162 h;
        h.x = __float2bfloat16(x.x);
        h.y = __float2bfloat16(x.y);
        ((__hip_bfloat162*)(Xh + (size_t)node * D))[lane] = h;
    }
    int d0 = lane * 2;
    float s0 = x.x * W[d0 * G + 0] + x.y * W[(d0 + 1) * G + 0];
    float s1 = x.x * W[d0 * G + 1] + x.y * W[(d0 + 1) * G + 1];
    float s2 = x.x * W[d0 * G + 2] + x.y * W[(d0 + 1) * G + 2];
    #pragma unroll
    for (int off = 32; off; off >>= 1) {
        s0 += __shfl_xor(s0, off);
        s1 += __shfl_xor(s1, off);
        s2 += __shfl_xor(s2, off);
    }
    s0 += b[0]; s1 += b[1]; s2 += b[2];     // T = 1.0
    float m = fmaxf(s0, fmaxf(s1, s2));
    float e0 = __expf(s0 - m), e1 = __expf(s1 - m), e2 = __expf(s2 - m);
    float inv = 1.0f / (e0 + e1 + e2);
    if (lane == 0) coeff[node] = make_float4(e0 * inv, e1 * inv, e2 * inv, 0.0f);
}

// ---------------------------------------------------------------------------
// Kernel 2: degree histogram (int atomics)
// ---------------------------------------------------------------------------
__global__ void lg_deg_kernel(const int* __restrict__ dst, int* __restrict__ deg, int E) {
    int e = (int)(blockIdx.x * (size_t)blockDim.x + threadIdx.x);
    if (e < E) atomicAdd(&deg[dst[e]], 1);
}

// ---------------------------------------------------------------------------
// Kernel 3a: block-level exclusive scan (coalesced), per-block totals.
// ---------------------------------------------------------------------------
__global__ void lg_scan_a_kernel(const int* __restrict__ deg, int* __restrict__ off,
                                 int* __restrict__ bsum, int n, int E) {
    __shared__ int lds[256];
    int tid = threadIdx.x;
    int t = blockIdx.x * 256 + tid;
    int v = (t < n) ? deg[t] : 0;
    lds[tid] = v;
    __syncthreads();
    #pragma unroll
    for (int d = 1; d < 256; d <<= 1) {
        int y = (tid >= d) ? lds[tid - d] : 0;
        __syncthreads();
        lds[tid] += y;
        __syncthreads();
    }
    if (t < n) off[t] = lds[tid] - v;            // exclusive within block
    if (tid == 255) bsum[blockIdx.x] = lds[255]; // block total
    if (t == 0) off[n] = E;                      // grand total known a priori
}

// ---------------------------------------------------------------------------
// Kernel 3b: add prefix of block sums; also init bucket write cursors
// cursor[bk] = off[bk*BN]  (exact bucket region base -> no overflow).
// ---------------------------------------------------------------------------
__global__ void lg_scan_b_kernel(int* __restrict__ off, const int* __restrict__ bsum,
                                 int* __restrict__ cursor, int n) {
    int b = blockIdx.x;
    int tid = threadIdx.x;
    int s = 0;
    for (int i = tid; i < b; i += 256) s += bsum[i];
    #pragma unroll
    for (int o = 32; o; o >>= 1) s += __shfl_xor(s, o);
    __shared__ int wsm[4];
    if ((tid & 63) == 0) wsm[tid >> 6] = s;
    __syncthreads();
    int S = wsm[0] + wsm[1] + wsm[2] + wsm[3];
    int t = b * 256 + tid;
    if (t < n) {
        int val = off[t] + S;
        off[t] = val;
        if ((tid & (BN - 1)) == 0) cursor[t / BN] = val;
    }
}

// ---------------------------------------------------------------------------
// Kernel 4: LDS-staged bucket binning. rec(u32) = src(16) | dst_low7 << 16.
// Per block: histogram -> scan -> LDS scatter -> bulk-reserve -> coalesced
// burst writes into exact bucket regions. Requires n <= 65536, nbuck <= 512.
// ---------------------------------------------------------------------------
__global__ __launch_bounds__(256) void lg_bin_kernel(
        const int* __restrict__ src, const int* __restrict__ dst,
        int* __restrict__ cursor, unsigned int* __restrict__ temp,
        int E, int nbuck) {
    __shared__ unsigned int stage[CH];                     // 32 KB
    __shared__ int hist[512], sc[512], hbase[512], hcnt[512], gbs[512];
    int tid = threadIdx.x;
    int e0 = blockIdx.x * CH;
    int ecnt = min(CH, E - e0);
    for (int i = tid; i < 512; i += 256) { hist[i] = 0; hcnt[i] = 0; }
    __syncthreads();
    // pass 1: histogram
    for (int k = tid; k < ecnt; k += 256) {
        int d = dst[e0 + k];
        atomicAdd(&hist[d >> 7], 1);
    }
    __syncthreads();
    // inclusive scan over 512 entries (2 per thread)
    int i0 = tid, i1 = tid + 256;
    sc[i0] = hist[i0]; sc[i1] = hist[i1];
    __syncthreads();
    #pragma unroll
    for (int d = 1; d < 512; d <<= 1) {
        int v0 = (i0 >= d) ? sc[i0 - d] : 0;
        int v1 = (i1 >= d) ? sc[i1 - d] : 0;
        __syncthreads();
        sc[i0] += v0; sc[i1] += v1;
        __syncthreads();
    }
    hbase[i0] = sc[i0] - hist[i0];
    hbase[i1] = sc[i1] - hist[i1];
    __syncthreads();
    // pass 2: scatter into stage (src/dst re-read: L2-hot)
    for (int k = tid; k < ecnt; k += 256) {
        int s = src[e0 + k], d = dst[e0 + k];
        int bk = d >> 7;
        int idx = hbase[bk] + atomicAdd(&hcnt[bk], 1);
        stage[idx] = ((unsigned int)s & 0xFFFFu) | (((unsigned int)d & 127u) << 16);
    }
    // bulk-reserve global ranges (one atomic per non-empty bucket)
    for (int i = tid; i < nbuck; i += 256) {
        int c = hist[i];
        gbs[i] = c ? atomicAdd(&cursor[i], c) : 0;
    }
    __syncthreads();
    // coalesced burst flush: one wave per bucket round-robin
    int wv = tid >> 6, ln = tid & 63;
    for (int bk = wv; bk < nbuck; bk += 4) {
        int c = hist[bk];
        if (!c) continue;
        int gb = gbs[bk], hb = hbase[bk];
        for (int j = ln; j < c; j += 64) temp[gb + j] = stage[hb + j];
    }
}

// ---------------------------------------------------------------------------
// Kernel 5: per-bucket sort + register-accumulate aggregation.
// One 1024-thread block (16 waves) per 128-node bucket.
// Phase 1: coalesced-read bucket records; compute w=dot3(coeff[s],coeff[d])
//          in f32; counting-sort-place (src16|w-bf16) into LDS stage using
//          exact per-node bases from off[] (only tiny int cursors atomic).
// Phase 2: wave wv handles nodes wv, wv+16, ...: wave-uniform LDS broadcast
//          of records, unroll-4 bf16 row gathers, REGISTER accumulation,
//          scale by 1/deg, coalesced float2 store. No global scatter writes.
// ---------------------------------------------------------------------------
__global__ __launch_bounds__(1024) void lg_sortagg_kernel(
        const __hip_bfloat16* __restrict__ Xh,
        const float4* __restrict__ coeff,
        const unsigned int* __restrict__ temp,
        const int* __restrict__ off,
        const int* __restrict__ deg,
        float* __restrict__ out, int n) {
    __shared__ unsigned int stage[CAP];    // 16 KB
    __shared__ float4 cdl[BN];             // 2 KB: dst coeffs
    __shared__ int nbase[BN], ncur[BN];    // 1 KB
    int tid = threadIdx.x;
    int wv = tid >> 6, ln = tid & 63;
    int nb0 = blockIdx.x * BN;
    int nv = min(BN, n - nb0);
    int rbeg = off[nb0];
    int rend = off[nb0 + nv];
    if (tid < nv) {
        cdl[tid] = coeff[nb0 + tid];
        nbase[tid] = off[nb0 + tid] - rbeg;
        ncur[tid] = 0;
    }
    __syncthreads();
    int count = rend - rbeg;

    if (count <= CAP) {
        // ---- phase 1: compute w + counting-sort into stage ----
        for (int k = tid; k < count; k += 1024) {
            unsigned int rec = temp[rbeg + k];
            int s = (int)(rec & 0xFFFFu);
            int d = (int)((rec >> 16) & 127u);
            float4 cs = coeff[s];
            float4 cd = cdl[d];
            float w = cs.x * cd.x + cs.y * cd.y + cs.z * cd.z;
            unsigned int wb = __float_as_uint(w);
            wb += 0x7FFFu + ((wb >> 16) & 1u);       // RNE to bf16
            int pos = nbase[d] + atomicAdd(&ncur[d], 1);
            stage[pos] = (rec & 0xFFFFu) | (wb & 0xFFFF0000u);
        }
        __syncthreads();
        // ---- phase 2: per-node register accumulation ----
        for (int i = wv; i < nv; i += 16) {
            int ibeg = nbase[i];
            int icnt = ncur[i];
            float accx = 0.0f, accy = 0.0f;
            int j = 0;
            for (; j + 3 < icnt; j += 4) {
                unsigned int r0 = stage[ibeg + j + 0];
                unsigned int r1 = stage[ibeg + j + 1];
                unsigned int r2 = stage[ibeg + j + 2];
                unsigned int r3 = stage[ibeg + j + 3];
                int s0 = (int)(r0 & 0xFFFFu), s1 = (int)(r1 & 0xFFFFu);
                int s2 = (int)(r2 & 0xFFFFu), s3 = (int)(r3 & 0xFFFFu);
                float w0 = __uint_as_float(r0 & 0xFFFF0000u);
                float w1 = __uint_as_float(r1 & 0xFFFF0000u);
                float w2 = __uint_as_float(r2 & 0xFFFF0000u);
                float w3 = __uint_as_float(r3 & 0xFFFF0000u);
                __hip_bfloat162 h0 = ((const __hip_bfloat162*)(Xh + (size_t)s0 * D))[ln];
                __hip_bfloat162 h1 = ((const __hip_bfloat162*)(Xh + (size_t)s1 * D))[ln];
                __hip_bfloat162 h2 = ((const __hip_bfloat162*)(Xh + (size_t)s2 * D))[ln];
                __hip_bfloat162 h3 = ((const __hip_bfloat162*)(Xh + (size_t)s3 * D))[ln];
                accx = fmaf(w0, __bfloat162float(h0.x), accx);
                accy = fmaf(w0, __bfloat162float(h0.y), accy);
                accx = fmaf(w1, __bfloat162float(h1.x), accx);
                accy = fmaf(w1, __bfloat162float(h1.y), accy);
                accx = fmaf(w2, __bfloat162float(h2.x), accx);
                accy = fmaf(w2, __bfloat162float(h2.y), accy);
                accx = fmaf(w3, __bfloat162float(h3.x), accx);
                accy = fmaf(w3, __bfloat162float(h3.y), accy);
            }
            for (; j < icnt; ++j) {
                unsigned int r0 = stage[ibeg + j];
                int s0 = (int)(r0 & 0xFFFFu);
                float w0 = __uint_as_float(r0 & 0xFFFF0000u);
                __hip_bfloat162 h0 = ((const __hip_bfloat162*)(Xh + (size_t)s0 * D))[ln];
                accx = fmaf(w0, __bfloat162float(h0.x), accx);
                accy = fmaf(w0, __bfloat162float(h0.y), accy);
            }
            float invd = 1.0f / fmaxf((float)icnt, 1.0f);
            ((float2*)(out + (size_t)(nb0 + i) * D))[ln] =
                make_float2(accx * invd, accy * invd);
        }
    } else {
        // ---- rare overflow path (bucket > CAP records): ballot scan ----
        for (int i = wv; i < nv; i += 16) {
            float4 cd = cdl[i];
            float accx = 0.0f, accy = 0.0f;
            for (int base = 0; base < count; base += 64) {
                int k = base + ln;
                unsigned int rec = (k < count) ? temp[rbeg + k] : 0u;
                bool ok = (k < count) && ((int)((rec >> 16) & 127u) == i);
                unsigned long long mask = __ballot(ok);
                while (mask) {
                    int bpos = __ffsll((long long)mask) - 1;
                    mask &= mask - 1;
                    unsigned int rr = __shfl(rec, bpos);
                    int s0 = (int)(rr & 0xFFFFu);
                    float4 cs = coeff[s0];
                    float w = cs.x * cd.x + cs.y * cd.y + cs.z * cd.z;
                    __hip_bfloat162 h0 = ((const __hip_bfloat162*)(Xh + (size_t)s0 * D))[ln];
                    accx = fmaf(w, __bfloat162float(h0.x), accx);
                    accy = fmaf(w, __bfloat162float(h0.y), accy);
                }
            }
            float invd = 1.0f / fmaxf((float)deg[nb0 + i], 1.0f);
            ((float2*)(out + (size_t)(nb0 + i) * D))[ln] =
                make_float2(accx * invd, accy * invd);
        }
    }
}

// ---------------------------------------------------------------------------
// Minimal-workspace / large-n fallback: float-atomic scatter
// ---------------------------------------------------------------------------
__global__ void lg_scatter_kernel(const float* __restrict__ X,
                                  const float4* __restrict__ coeff,
                                  const int* __restrict__ src, const int* __restrict__ dst,
                                  float* __restrict__ out, int E) {
    int e = (int)((blockIdx.x * (size_t)blockDim.x + threadIdx.x) >> 6);
    int lane = threadIdx.x & 63;
    if (e >= E) return;
    int s = src[e], d = dst[e];
    float4 cs = coeff[s], cd = coeff[d];
    float se = cs.x * cd.x + cs.y * cd.y + cs.z * cd.z;
    float2 x = ((const float2*)(X + (size_t)s * D))[lane];
    atomicAdd(&out[(size_t)d * D + lane * 2 + 0], se * x.x);
    atomicAdd(&out[(size_t)d * D + lane * 2 + 1], se * x.y);
}

__global__ void lg_scale_kernel(float* __restrict__ out, const int* __restrict__ deg, int n) {
    int node = (int)((blockIdx.x * (size_t)blockDim.x + threadIdx.x) >> 6);
    int lane = threadIdx.x & 63;
    if (node >= n) return;
    float invd = 1.0f / fmaxf((float)deg[node], 1.0f);
    float2* p = (float2*)(out + (size_t)node * D);
    float2 v = p[lane];
    p[lane] = make_float2(v.x * invd, v.y * invd);
}

extern "C" void kernel_launch(void* const* d_in, const int* in_sizes, int n_in,
                              void* d_out, int out_size, void* d_ws, size_t ws_size,
                              hipStream_t stream) {
    const float* X   = (const float*)d_in[0];
    const int*   src = (const int*)d_in[1];
    const int*   dst = (const int*)d_in[2];
    const float* W   = (const float*)d_in[3];
    const float* b   = (const float*)d_in[4];
    float* out = (float*)d_out;
    int n = in_sizes[0] / D;
    int E = in_sizes[1];

    int nb    = (n + 255) / 256;        // scan blocks
    int nbuck = (n + BN - 1) / BN;      // dst buckets

    char* ws = (char*)d_ws;
    size_t p = 0;
    auto alloc = [&](size_t bytes) -> void* {
        void* r = ws + p;
        p = (p + bytes + 255) & ~(size_t)255;
        return r;
    };
    float4* coeff  = (float4*)alloc((size_t)n * sizeof(float4));
    int*    deg    = (int*)alloc((size_t)n * sizeof(int));
    int*    off    = (int*)alloc((size_t)(n + 1) * sizeof(int));
    int*    bsum   = (int*)alloc((size_t)nb * sizeof(int));
    int*    cursor = (int*)alloc((size_t)nbuck * sizeof(int));
    unsigned int* temp = (unsigned int*)alloc((size_t)E * sizeof(unsigned int));
    __hip_bfloat16* Xh = (__hip_bfloat16*)alloc((size_t)n * D * sizeof(__hip_bfloat16));
    size_t p_full = p;

    int node_blocks = (n + 3) / 4;      // 4 waves (nodes) per 256-thread block
    int edge_blocks = (E + 255) / 256;
    int bin_blocks  = (E + CH - 1) / CH;

    bool fast_ok = (n <= 65536) && (nbuck <= 512) && (p_full <= ws_size);
    if (fast_ok) {
        hipMemsetAsync(deg, 0, (size_t)n * sizeof(int), stream);
        lg_coeff_kernel<<<node_blocks, 256, 0, stream>>>(X, W, b, coeff, Xh, n);
        lg_deg_kernel<<<edge_blocks, 256, 0, stream>>>(dst, deg, E);
        lg_scan_a_kernel<<<nb, 256, 0, stream>>>(deg, off, bsum, n, E);
        lg_scan_b_kernel<<<nb, 256, 0, stream>>>(off, bsum, cursor, n);
        lg_bin_kernel<<<bin_blocks, 256, 0, stream>>>(src, dst, cursor, temp, E, nbuck);
        lg_sortagg_kernel<<<nbuck, 1024, 0, stream>>>(Xh, coeff, temp, off, deg, out, n);
    } else {
        // fallback (~1 MB): coeff + deg; atomic scatter
        hipMemsetAsync(deg, 0, (size_t)n * sizeof(int), stream);
        hipMemsetAsync(out, 0, (size_t)n * D * sizeof(float), stream);
        lg_coeff_kernel<<<node_blocks, 256, 0, stream>>>(X, W, b, coeff, nullptr, n);
        lg_deg_kernel<<<edge_blocks, 256, 0, stream>>>(dst, deg, E);
        lg_scatter_kernel<<<(E + 3) / 4, 256, 0, stream>>>(X, coeff, src, dst, out, E);
        lg_scale_kernel<<<node_blocks, 256, 0, stream>>>(out, deg, n);
    }
}

// Round 7
// 111.761 us; speedup vs baseline: 7.3863x; 1.2185x over previous
//
#include <hip/hip_runtime.h>
#include <hip/hip_bf16.h>

#define D 128            // EMBED_DIM
#define G 3              // NUM_GROUPS
#define BN 128           // dst nodes per bucket (7 bits in record)
#define CH 8192          // edges per bin block
#define BIN_T 1024       // threads per bin block (16 waves: TLP for latency hiding)
#define CAP 4096         // max records staged per bucket in sortagg (mean 2048)

// ---------------------------------------------------------------------------
// Kernel 1: per-node linear(128->3) + softmax -> coeff[n] (float4, w=0)
// Also emits a bf16 copy of X for the gather phase (halves gather traffic).
// ---------------------------------------------------------------------------
__global__ void lg_coeff_kernel(const float* __restrict__ X,
                                const float* __restrict__ W,
                                const float* __restrict__ b,
                                float4* __restrict__ coeff,
                                __hip_bfloat16* __restrict__ Xh,   // may be null
                                int n) {
    int node = (int)((blockIdx.x * (size_t)blockDim.x + threadIdx.x) >> 6);
    int lane = threadIdx.x & 63;
    if (node >= n) return;
    float2 x = ((const float2*)(X + (size_t)node * D))[lane];
    if (Xh) {
        __hip_bfloat162 h;
        h.x = __float2bfloat16(x.x);
        h.y = __float2bfloat16(x.y);
        ((__hip_bfloat162*)(Xh + (size_t)node * D))[lane] = h;
    }
    int d0 = lane * 2;
    float s0 = x.x * W[d0 * G + 0] + x.y * W[(d0 + 1) * G + 0];
    float s1 = x.x * W[d0 * G + 1] + x.y * W[(d0 + 1) * G + 1];
    float s2 = x.x * W[d0 * G + 2] + x.y * W[(d0 + 1) * G + 2];
    #pragma unroll
    for (int off = 32; off; off >>= 1) {
        s0 += __shfl_xor(s0, off);
        s1 += __shfl_xor(s1, off);
        s2 += __shfl_xor(s2, off);
    }
    s0 += b[0]; s1 += b[1]; s2 += b[2];     // T = 1.0
    float m = fmaxf(s0, fmaxf(s1, s2));
    float e0 = __expf(s0 - m), e1 = __expf(s1 - m), e2 = __expf(s2 - m);
    float inv = 1.0f / (e0 + e1 + e2);
    if (lane == 0) coeff[node] = make_float4(e0 * inv, e1 * inv, e2 * inv, 0.0f);
}

// ---------------------------------------------------------------------------
// Kernel 2: degree histogram (int atomics)
// ---------------------------------------------------------------------------
__global__ void lg_deg_kernel(const int* __restrict__ dst, int* __restrict__ deg, int E) {
    int e = (int)(blockIdx.x * (size_t)blockDim.x + threadIdx.x);
    if (e < E) atomicAdd(&deg[dst[e]], 1);
}

// ---------------------------------------------------------------------------
// Kernel 3a: block-level exclusive scan (coalesced), per-block totals.
// ---------------------------------------------------------------------------
__global__ void lg_scan_a_kernel(const int* __restrict__ deg, int* __restrict__ off,
                                 int* __restrict__ bsum, int n, int E) {
    __shared__ int lds[256];
    int tid = threadIdx.x;
    int t = blockIdx.x * 256 + tid;
    int v = (t < n) ? deg[t] : 0;
    lds[tid] = v;
    __syncthreads();
    #pragma unroll
    for (int d = 1; d < 256; d <<= 1) {
        int y = (tid >= d) ? lds[tid - d] : 0;
        __syncthreads();
        lds[tid] += y;
        __syncthreads();
    }
    if (t < n) off[t] = lds[tid] - v;            // exclusive within block
    if (tid == 255) bsum[blockIdx.x] = lds[255]; // block total
    if (t == 0) off[n] = E;                      // grand total known a priori
}

// ---------------------------------------------------------------------------
// Kernel 3b: add prefix of block sums; also init bucket write cursors
// cursor[bk] = off[bk*BN]  (exact bucket region base -> no overflow).
// ---------------------------------------------------------------------------
__global__ void lg_scan_b_kernel(int* __restrict__ off, const int* __restrict__ bsum,
                                 int* __restrict__ cursor, int n) {
    int b = blockIdx.x;
    int tid = threadIdx.x;
    int s = 0;
    for (int i = tid; i < b; i += 256) s += bsum[i];
    #pragma unroll
    for (int o = 32; o; o >>= 1) s += __shfl_xor(s, o);
    __shared__ int wsm[4];
    if ((tid & 63) == 0) wsm[tid >> 6] = s;
    __syncthreads();
    int S = wsm[0] + wsm[1] + wsm[2] + wsm[3];
    int t = b * 256 + tid;
    if (t < n) {
        int val = off[t] + S;
        off[t] = val;
        if ((tid & (BN - 1)) == 0) cursor[t / BN] = val;
    }
}

// ---------------------------------------------------------------------------
// Kernel 4: LDS-staged bucket binning. rec(u32) = src(16) | dst_low7 << 16.
// 1024 threads/block, CH=8192 edges: 8 edges/thread held in REGISTERS
// (loaded once, coalesced). histogram -> scan -> LDS scatter ->
// bulk-reserve -> coalesced burst flush into exact bucket regions.
// Requires n <= 65536, nbuck <= 512.
// ---------------------------------------------------------------------------
__global__ __launch_bounds__(BIN_T) void lg_bin_kernel(
        const int* __restrict__ src, const int* __restrict__ dst,
        int* __restrict__ cursor, unsigned int* __restrict__ temp,
        int E, int nbuck) {
    __shared__ unsigned int stage[CH];                     // 32 KB
    __shared__ int hist[512], sc[512], hbase[512], hcnt[512], gbs[512];
    int tid = threadIdx.x;
    int e0 = blockIdx.x * CH;
    int ecnt = min(CH, E - e0);
    for (int i = tid; i < 512; i += BIN_T) { hist[i] = 0; hcnt[i] = 0; }
    __syncthreads();
    // load edges to registers (coalesced, once) + histogram
    int rs[CH / BIN_T], rd[CH / BIN_T];
    #pragma unroll
    for (int u = 0; u < CH / BIN_T; ++u) {
        int k = tid + u * BIN_T;
        if (k < ecnt) {
            rs[u] = src[e0 + k];
            rd[u] = dst[e0 + k];
            atomicAdd(&hist[rd[u] >> 7], 1);
        } else rd[u] = -1;
    }
    __syncthreads();
    // inclusive scan over 512 entries (first 512 threads own 1 each)
    if (tid < 512) sc[tid] = hist[tid];
    __syncthreads();
    #pragma unroll
    for (int d = 1; d < 512; d <<= 1) {
        int v = (tid < 512 && tid >= d) ? sc[tid - d] : 0;
        __syncthreads();
        if (tid < 512) sc[tid] += v;
        __syncthreads();
    }
    if (tid < 512) hbase[tid] = sc[tid] - hist[tid];
    __syncthreads();
    // scatter into stage from registers
    #pragma unroll
    for (int u = 0; u < CH / BIN_T; ++u) {
        if (rd[u] >= 0) {
            int bk = rd[u] >> 7;
            int idx = hbase[bk] + atomicAdd(&hcnt[bk], 1);
            stage[idx] = ((unsigned int)rs[u] & 0xFFFFu) |
                         (((unsigned int)rd[u] & 127u) << 16);
        }
    }
    // bulk-reserve global ranges (one atomic per non-empty bucket)
    for (int i = tid; i < nbuck; i += BIN_T) {
        int c = hist[i];
        gbs[i] = c ? atomicAdd(&cursor[i], c) : 0;
    }
    __syncthreads();   // covers scatter + reserve
    // coalesced burst flush: one wave per bucket round-robin
    int wv = tid >> 6, ln = tid & 63;
    for (int bk = wv; bk < nbuck; bk += BIN_T / 64) {
        int c = hist[bk];
        if (!c) continue;
        int gb = gbs[bk], hb = hbase[bk];
        for (int j = ln; j < c; j += 64) temp[gb + j] = stage[hb + j];
    }
}

// ---------------------------------------------------------------------------
// Kernel 5: per-bucket sort + register-accumulate aggregation.
// One 1024-thread block (16 waves) per 128-node bucket.
// Phase 1: coalesced-read bucket records; compute w=dot3(coeff[s],coeff[d])
//          in f32; counting-sort-place (src16|w-bf16) into LDS stage using
//          exact per-node bases from off[] (only tiny int cursors atomic).
// Phase 2: wave wv handles nodes wv, wv+16, ...: wave-uniform LDS reads
//          of records, unroll-4 bf16 row gathers, REGISTER accumulation,
//          scale by 1/deg, coalesced float2 store. No global scatter writes.
// ---------------------------------------------------------------------------
__global__ __launch_bounds__(1024) void lg_sortagg_kernel(
        const __hip_bfloat16* __restrict__ Xh,
        const float4* __restrict__ coeff,
        const unsigned int* __restrict__ temp,
        const int* __restrict__ off,
        const int* __restrict__ deg,
        float* __restrict__ out, int n) {
    __shared__ unsigned int stage[CAP];    // 16 KB
    __shared__ float4 cdl[BN];             // 2 KB: dst coeffs
    __shared__ int nbase[BN], ncur[BN];    // 1 KB
    int tid = threadIdx.x;
    int wv = tid >> 6, ln = tid & 63;
    int nb0 = blockIdx.x * BN;
    int nv = min(BN, n - nb0);
    int rbeg = off[nb0];
    int rend = off[nb0 + nv];
    if (tid < nv) {
        cdl[tid] = coeff[nb0 + tid];
        nbase[tid] = off[nb0 + tid] - rbeg;
        ncur[tid] = 0;
    }
    __syncthreads();
    int count = rend - rbeg;

    if (count <= CAP) {
        // ---- phase 1: compute w + counting-sort into stage ----
        for (int k = tid; k < count; k += 1024) {
            unsigned int rec = temp[rbeg + k];
            int s = (int)(rec & 0xFFFFu);
            int d = (int)((rec >> 16) & 127u);
            float4 cs = coeff[s];
            float4 cd = cdl[d];
            float w = cs.x * cd.x + cs.y * cd.y + cs.z * cd.z;
            unsigned int wb = __float_as_uint(w);
            wb += 0x7FFFu + ((wb >> 16) & 1u);       // RNE to bf16
            int pos = nbase[d] + atomicAdd(&ncur[d], 1);
            stage[pos] = (rec & 0xFFFFu) | (wb & 0xFFFF0000u);
        }
        __syncthreads();
        // ---- phase 2: per-node register accumulation ----
        for (int i = wv; i < nv; i += 16) {
            int ibeg = nbase[i];
            int icnt = ncur[i];
            float accx = 0.0f, accy = 0.0f;
            int j = 0;
            for (; j + 3 < icnt; j += 4) {
                unsigned int r0 = stage[ibeg + j + 0];
                unsigned int r1 = stage[ibeg + j + 1];
                unsigned int r2 = stage[ibeg + j + 2];
                unsigned int r3 = stage[ibeg + j + 3];
                int s0 = (int)(r0 & 0xFFFFu), s1 = (int)(r1 & 0xFFFFu);
                int s2 = (int)(r2 & 0xFFFFu), s3 = (int)(r3 & 0xFFFFu);
                float w0 = __uint_as_float(r0 & 0xFFFF0000u);
                float w1 = __uint_as_float(r1 & 0xFFFF0000u);
                float w2 = __uint_as_float(r2 & 0xFFFF0000u);
                float w3 = __uint_as_float(r3 & 0xFFFF0000u);
                __hip_bfloat162 h0 = ((const __hip_bfloat162*)(Xh + (size_t)s0 * D))[ln];
                __hip_bfloat162 h1 = ((const __hip_bfloat162*)(Xh + (size_t)s1 * D))[ln];
                __hip_bfloat162 h2 = ((const __hip_bfloat162*)(Xh + (size_t)s2 * D))[ln];
                __hip_bfloat162 h3 = ((const __hip_bfloat162*)(Xh + (size_t)s3 * D))[ln];
                accx = fmaf(w0, __bfloat162float(h0.x), accx);
                accy = fmaf(w0, __bfloat162float(h0.y), accy);
                accx = fmaf(w1, __bfloat162float(h1.x), accx);
                accy = fmaf(w1, __bfloat162float(h1.y), accy);
                accx = fmaf(w2, __bfloat162float(h2.x), accx);
                accy = fmaf(w2, __bfloat162float(h2.y), accy);
                accx = fmaf(w3, __bfloat162float(h3.x), accx);
                accy = fmaf(w3, __bfloat162float(h3.y), accy);
            }
            for (; j < icnt; ++j) {
                unsigned int r0 = stage[ibeg + j];
                int s0 = (int)(r0 & 0xFFFFu);
                float w0 = __uint_as_float(r0 & 0xFFFF0000u);
                __hip_bfloat162 h0 = ((const __hip_bfloat162*)(Xh + (size_t)s0 * D))[ln];
                accx = fmaf(w0, __bfloat162float(h0.x), accx);
                accy = fmaf(w0, __bfloat162float(h0.y), accy);
            }
            float invd = 1.0f / fmaxf((float)icnt, 1.0f);
            ((float2*)(out + (size_t)(nb0 + i) * D))[ln] =
                make_float2(accx * invd, accy * invd);
        }
    } else {
        // ---- rare overflow path (bucket > CAP records): ballot scan ----
        for (int i = wv; i < nv; i += 16) {
            float4 cd = cdl[i];
            float accx = 0.0f, accy = 0.0f;
            for (int base = 0; base < count; base += 64) {
                int k = base + ln;
                unsigned int rec = (k < count) ? temp[rbeg + k] : 0u;
                bool ok = (k < count) && ((int)((rec >> 16) & 127u) == i);
                unsigned long long mask = __ballot(ok);
                while (mask) {
                    int bpos = __ffsll((long long)mask) - 1;
                    mask &= mask - 1;
                    unsigned int rr = __shfl(rec, bpos);
                    int s0 = (int)(rr & 0xFFFFu);
                    float4 cs = coeff[s0];
                    float w = cs.x * cd.x + cs.y * cd.y + cs.z * cd.z;
                    __hip_bfloat162 h0 = ((const __hip_bfloat162*)(Xh + (size_t)s0 * D))[ln];
                    accx = fmaf(w, __bfloat162float(h0.x), accx);
                    accy = fmaf(w, __bfloat162float(h0.y), accy);
                }
            }
            float invd = 1.0f / fmaxf((float)deg[nb0 + i], 1.0f);
            ((float2*)(out + (size_t)(nb0 + i) * D))[ln] =
                make_float2(accx * invd, accy * invd);
        }
    }
}

// ---------------------------------------------------------------------------
// Minimal-workspace / large-n fallback: float-atomic scatter
// ---------------------------------------------------------------------------
__global__ void lg_scatter_kernel(const float* __restrict__ X,
                                  const float4* __restrict__ coeff,
                                  const int* __restrict__ src, const int* __restrict__ dst,
                                  float* __restrict__ out, int E) {
    int e = (int)((blockIdx.x * (size_t)blockDim.x + threadIdx.x) >> 6);
    int lane = threadIdx.x & 63;
    if (e >= E) return;
    int s = src[e], d = dst[e];
    float4 cs = coeff[s], cd = coeff[d];
    float se = cs.x * cd.x + cs.y * cd.y + cs.z * cd.z;
    float2 x = ((const float2*)(X + (size_t)s * D))[lane];
    atomicAdd(&out[(size_t)d * D + lane * 2 + 0], se * x.x);
    atomicAdd(&out[(size_t)d * D + lane * 2 + 1], se * x.y);
}

__global__ void lg_scale_kernel(float* __restrict__ out, const int* __restrict__ deg, int n) {
    int node = (int)((blockIdx.x * (size_t)blockDim.x + threadIdx.x) >> 6);
    int lane = threadIdx.x & 63;
    if (node >= n) return;
    float invd = 1.0f / fmaxf((float)deg[node], 1.0f);
    float2* p = (float2*)(out + (size_t)node * D);
    float2 v = p[lane];
    p[lane] = make_float2(v.x * invd, v.y * invd);
}

extern "C" void kernel_launch(void* const* d_in, const int* in_sizes, int n_in,
                              void* d_out, int out_size, void* d_ws, size_t ws_size,
                              hipStream_t stream) {
    const float* X   = (const float*)d_in[0];
    const int*   src = (const int*)d_in[1];
    const int*   dst = (const int*)d_in[2];
    const float* W   = (const float*)d_in[3];
    const float* b   = (const float*)d_in[4];
    float* out = (float*)d_out;
    int n = in_sizes[0] / D;
    int E = in_sizes[1];

    int nb    = (n + 255) / 256;        // scan blocks
    int nbuck = (n + BN - 1) / BN;      // dst buckets

    char* ws = (char*)d_ws;
    size_t p = 0;
    auto alloc = [&](size_t bytes) -> void* {
        void* r = ws + p;
        p = (p + bytes + 255) & ~(size_t)255;
        return r;
    };
    float4* coeff  = (float4*)alloc((size_t)n * sizeof(float4));
    int*    deg    = (int*)alloc((size_t)n * sizeof(int));
    int*    off    = (int*)alloc((size_t)(n + 1) * sizeof(int));
    int*    bsum   = (int*)alloc((size_t)nb * sizeof(int));
    int*    cursor = (int*)alloc((size_t)nbuck * sizeof(int));
    unsigned int* temp = (unsigned int*)alloc((size_t)E * sizeof(unsigned int));
    __hip_bfloat16* Xh = (__hip_bfloat16*)alloc((size_t)n * D * sizeof(__hip_bfloat16));
    size_t p_full = p;

    int node_blocks = (n + 3) / 4;      // 4 waves (nodes) per 256-thread block
    int edge_blocks = (E + 255) / 256;
    int bin_blocks  = (E + CH - 1) / CH;

    bool fast_ok = (n <= 65536) && (nbuck <= 512) && (p_full <= ws_size);
    if (fast_ok) {
        hipMemsetAsync(deg, 0, (size_t)n * sizeof(int), stream);
        lg_coeff_kernel<<<node_blocks, 256, 0, stream>>>(X, W, b, coeff, Xh, n);
        lg_deg_kernel<<<edge_blocks, 256, 0, stream>>>(dst, deg, E);
        lg_scan_a_kernel<<<nb, 256, 0, stream>>>(deg, off, bsum, n, E);
        lg_scan_b_kernel<<<nb, 256, 0, stream>>>(off, bsum, cursor, n);
        lg_bin_kernel<<<bin_blocks, BIN_T, 0, stream>>>(src, dst, cursor, temp, E, nbuck);
        lg_sortagg_kernel<<<nbuck, 1024, 0, stream>>>(Xh, coeff, temp, off, deg, out, n);
    } else {
        // fallback (~1 MB): coeff + deg; atomic scatter
        hipMemsetAsync(deg, 0, (size_t)n * sizeof(int), stream);
        hipMemsetAsync(out, 0, (size_t)n * D * sizeof(float), stream);
        lg_coeff_kernel<<<node_blocks, 256, 0, stream>>>(X, W, b, coeff, nullptr, n);
        lg_deg_kernel<<<edge_blocks, 256, 0, stream>>>(dst, deg, E);
        lg_scatter_kernel<<<(E + 3) / 4, 256, 0, stream>>>(X, coeff, src, dst, out, E);
        lg_scale_kernel<<<node_blocks, 256, 0, stream>>>(out, deg, n);
    }
}

// Round 8
// 75.898 us; speedup vs baseline: 10.8765x; 1.4725x over previous
//
#include <hip/hip_runtime.h>
#include <hip/hip_bf16.h>

#define D 128            // EMBED_DIM
#define G 3              // NUM_GROUPS
#define BN 128           // dst nodes per bucket (7 bits in record)
#define CH 8192          // edges per bin/bcount block
#define BIN_T 1024       // threads per bin block (16 waves: TLP for latency hiding)
#define CAP 4096         // max records staged per bucket in sortagg (mean 2048)

// ---------------------------------------------------------------------------
// Kernel 1: per-node linear(128->3) + softmax -> coeff[n] (float4, w=0)
// Also emits bf16 copy of X (halves gather traffic) and zeroes bcnt (block 0)
// so no hipMemsetAsync is needed in the fast path (the rocclr fill kernel
// cost 44us/replay for a 200KB fill).
// ---------------------------------------------------------------------------
__global__ void lg_coeff_kernel(const float* __restrict__ X,
                                const float* __restrict__ W,
                                const float* __restrict__ b,
                                float4* __restrict__ coeff,
                                __hip_bfloat16* __restrict__ Xh,   // may be null
                                int* __restrict__ bcnt, int nbuck, // may be null
                                int n) {
    if (bcnt && blockIdx.x == 0) {
        for (int i = threadIdx.x; i < nbuck; i += 256) bcnt[i] = 0;
    }
    int node = (int)((blockIdx.x * (size_t)blockDim.x + threadIdx.x) >> 6);
    int lane = threadIdx.x & 63;
    if (node >= n) return;
    float2 x = ((const float2*)(X + (size_t)node * D))[lane];
    if (Xh) {
        __hip_bfloat162 h;
        h.x = __float2bfloat16(x.x);
        h.y = __float2bfloat16(x.y);
        ((__hip_bfloat162*)(Xh + (size_t)node * D))[lane] = h;
    }
    int d0 = lane * 2;
    float s0 = x.x * W[d0 * G + 0] + x.y * W[(d0 + 1) * G + 0];
    float s1 = x.x * W[d0 * G + 1] + x.y * W[(d0 + 1) * G + 1];
    float s2 = x.x * W[d0 * G + 2] + x.y * W[(d0 + 1) * G + 2];
    #pragma unroll
    for (int off = 32; off; off >>= 1) {
        s0 += __shfl_xor(s0, off);
        s1 += __shfl_xor(s1, off);
        s2 += __shfl_xor(s2, off);
    }
    s0 += b[0]; s1 += b[1]; s2 += b[2];     // T = 1.0
    float m = fmaxf(s0, fmaxf(s1, s2));
    float e0 = __expf(s0 - m), e1 = __expf(s1 - m), e2 = __expf(s2 - m);
    float inv = 1.0f / (e0 + e1 + e2);
    if (lane == 0) coeff[node] = make_float4(e0 * inv, e1 * inv, e2 * inv, 0.0f);
}

// ---------------------------------------------------------------------------
// Kernel 2: bucket-count histogram, LDS-pre-aggregated (one global atomic
// per (block,bucket) instead of per edge).
// ---------------------------------------------------------------------------
__global__ __launch_bounds__(1024) void lg_bcount_kernel(
        const int* __restrict__ dst, int* __restrict__ bcnt, int E, int nbuck) {
    __shared__ int h[512];
    int tid = threadIdx.x;
    if (tid < 512) h[tid] = 0;
    __syncthreads();
    int e0 = blockIdx.x * CH;
    int ecnt = min(CH, E - e0);
    for (int k = tid; k < ecnt; k += 1024)
        atomicAdd(&h[dst[e0 + k] >> 7], 1);
    __syncthreads();
    if (tid < nbuck && h[tid]) atomicAdd(&bcnt[tid], h[tid]);
}

// ---------------------------------------------------------------------------
// Kernel 3: single-block scan of bucket counts -> boff (exclusive) + cursor.
// nbuck <= 512. Tiny (~2us).
// ---------------------------------------------------------------------------
__global__ __launch_bounds__(512) void lg_bscan_kernel(
        const int* __restrict__ bcnt, int* __restrict__ boff,
        int* __restrict__ cursor, int nbuck, int E) {
    __shared__ int sc[512];
    int tid = threadIdx.x;
    int v = (tid < nbuck) ? bcnt[tid] : 0;
    sc[tid] = v;
    __syncthreads();
    #pragma unroll
    for (int d = 1; d < 512; d <<= 1) {
        int y = (tid >= d) ? sc[tid - d] : 0;
        __syncthreads();
        sc[tid] += y;
        __syncthreads();
    }
    if (tid < nbuck) {
        int excl = sc[tid] - v;
        boff[tid] = excl;
        cursor[tid] = excl;
    }
    if (tid == 0) boff[nbuck] = E;
}

// ---------------------------------------------------------------------------
// Kernel 4: LDS-staged bucket binning. rec(u32) = src(16) | dst_low7 << 16.
// 1024 threads/block, CH=8192 edges: 8 edges/thread held in REGISTERS.
// histogram -> scan -> LDS scatter -> bulk-reserve -> coalesced burst flush
// into exact bucket regions. Requires n <= 65536, nbuck <= 512.
// ---------------------------------------------------------------------------
__global__ __launch_bounds__(BIN_T) void lg_bin_kernel(
        const int* __restrict__ src, const int* __restrict__ dst,
        int* __restrict__ cursor, unsigned int* __restrict__ temp,
        int E, int nbuck) {
    __shared__ unsigned int stage[CH];                     // 32 KB
    __shared__ int hist[512], sc[512], hbase[512], hcnt[512], gbs[512];
    int tid = threadIdx.x;
    int e0 = blockIdx.x * CH;
    int ecnt = min(CH, E - e0);
    for (int i = tid; i < 512; i += BIN_T) { hist[i] = 0; hcnt[i] = 0; }
    __syncthreads();
    // load edges to registers (coalesced, once) + histogram
    int rs[CH / BIN_T], rd[CH / BIN_T];
    #pragma unroll
    for (int u = 0; u < CH / BIN_T; ++u) {
        int k = tid + u * BIN_T;
        if (k < ecnt) {
            rs[u] = src[e0 + k];
            rd[u] = dst[e0 + k];
            atomicAdd(&hist[rd[u] >> 7], 1);
        } else rd[u] = -1;
    }
    __syncthreads();
    // inclusive scan over 512 entries
    if (tid < 512) sc[tid] = hist[tid];
    __syncthreads();
    #pragma unroll
    for (int d = 1; d < 512; d <<= 1) {
        int v = (tid < 512 && tid >= d) ? sc[tid - d] : 0;
        __syncthreads();
        if (tid < 512) sc[tid] += v;
        __syncthreads();
    }
    if (tid < 512) hbase[tid] = sc[tid] - hist[tid];
    __syncthreads();
    // scatter into stage from registers
    #pragma unroll
    for (int u = 0; u < CH / BIN_T; ++u) {
        if (rd[u] >= 0) {
            int bk = rd[u] >> 7;
            int idx = hbase[bk] + atomicAdd(&hcnt[bk], 1);
            stage[idx] = ((unsigned int)rs[u] & 0xFFFFu) |
                         (((unsigned int)rd[u] & 127u) << 16);
        }
    }
    // bulk-reserve global ranges (one atomic per non-empty bucket)
    for (int i = tid; i < nbuck; i += BIN_T) {
        int c = hist[i];
        gbs[i] = c ? atomicAdd(&cursor[i], c) : 0;
    }
    __syncthreads();   // covers scatter + reserve
    // coalesced burst flush: one wave per bucket round-robin
    int wv = tid >> 6, ln = tid & 63;
    for (int bk = wv; bk < nbuck; bk += BIN_T / 64) {
        int c = hist[bk];
        if (!c) continue;
        int gb = gbs[bk], hb = hbase[bk];
        for (int j = ln; j < c; j += 64) temp[gb + j] = stage[hb + j];
    }
}

// ---------------------------------------------------------------------------
// Kernel 5: per-bucket sort + register-accumulate aggregation.
// One 1024-thread block (16 waves) per 128-node bucket.
// Records held in 4 static registers/thread; per-node counts/bases computed
// INTERNALLY (LDS int histogram + 7-step scan) -- no per-node global offsets
// or deg array needed. Then counting-sort into LDS stage and per-node
// register accumulation with bf16 row gathers. Degree = internal count.
// ---------------------------------------------------------------------------
__global__ __launch_bounds__(1024) void lg_sortagg_kernel(
        const __hip_bfloat16* __restrict__ Xh,
        const float4* __restrict__ coeff,
        const unsigned int* __restrict__ temp,
        const int* __restrict__ boff,
        float* __restrict__ out, int n) {
    __shared__ unsigned int stage[CAP];    // 16 KB
    __shared__ float4 cdl[BN];             // 2 KB: dst coeffs
    __shared__ int nhist[BN], scn[BN], nbase[BN], ncur[BN];  // 2 KB
    int tid = threadIdx.x;
    int wv = tid >> 6, ln = tid & 63;
    int nb0 = blockIdx.x * BN;
    int nv = min(BN, n - nb0);
    int rbeg = boff[blockIdx.x];
    int rend = boff[blockIdx.x + 1];
    int count = rend - rbeg;
    if (tid < BN) { nhist[tid] = 0; ncur[tid] = 0; }
    if (tid < nv) cdl[tid] = coeff[nb0 + tid];
    __syncthreads();

    if (count <= CAP) {
        // ---- load records to registers + per-node histogram ----
        int k0 = tid, k1 = tid + 1024, k2 = tid + 2048, k3 = tid + 3072;
        unsigned int r0 = 0, r1 = 0, r2 = 0, r3 = 0;
        if (k0 < count) { r0 = temp[rbeg + k0]; atomicAdd(&nhist[(r0 >> 16) & 127u], 1); }
        if (k1 < count) { r1 = temp[rbeg + k1]; atomicAdd(&nhist[(r1 >> 16) & 127u], 1); }
        if (k2 < count) { r2 = temp[rbeg + k2]; atomicAdd(&nhist[(r2 >> 16) & 127u], 1); }
        if (k3 < count) { r3 = temp[rbeg + k3]; atomicAdd(&nhist[(r3 >> 16) & 127u], 1); }
        __syncthreads();
        // ---- exclusive scan of per-node counts ----
        if (tid < BN) scn[tid] = nhist[tid];
        __syncthreads();
        #pragma unroll
        for (int d = 1; d < BN; d <<= 1) {
            int v = (tid < BN && tid >= d) ? scn[tid - d] : 0;
            __syncthreads();
            if (tid < BN) scn[tid] += v;
            __syncthreads();
        }
        if (tid < BN) nbase[tid] = scn[tid] - nhist[tid];
        __syncthreads();
        // ---- compute w + counting-sort into stage ----
        auto place = [&](unsigned int rec) {
            int s = (int)(rec & 0xFFFFu);
            int d = (int)((rec >> 16) & 127u);
            float4 cs = coeff[s];
            float4 cd = cdl[d];
            float w = cs.x * cd.x + cs.y * cd.y + cs.z * cd.z;
            unsigned int wb = __float_as_uint(w);
            wb += 0x7FFFu + ((wb >> 16) & 1u);       // RNE to bf16
            int pos = nbase[d] + atomicAdd(&ncur[d], 1);
            stage[pos] = (rec & 0xFFFFu) | (wb & 0xFFFF0000u);
        };
        if (k0 < count) place(r0);
        if (k1 < count) place(r1);
        if (k2 < count) place(r2);
        if (k3 < count) place(r3);
        __syncthreads();
        // ---- per-node register accumulation ----
        for (int i = wv; i < nv; i += 16) {
            int ibeg = nbase[i];
            int icnt = nhist[i];
            float accx = 0.0f, accy = 0.0f;
            int j = 0;
            for (; j + 3 < icnt; j += 4) {
                unsigned int q0 = stage[ibeg + j + 0];
                unsigned int q1 = stage[ibeg + j + 1];
                unsigned int q2 = stage[ibeg + j + 2];
                unsigned int q3 = stage[ibeg + j + 3];
                int s0 = (int)(q0 & 0xFFFFu), s1 = (int)(q1 & 0xFFFFu);
                int s2 = (int)(q2 & 0xFFFFu), s3 = (int)(q3 & 0xFFFFu);
                float w0 = __uint_as_float(q0 & 0xFFFF0000u);
                float w1 = __uint_as_float(q1 & 0xFFFF0000u);
                float w2 = __uint_as_float(q2 & 0xFFFF0000u);
                float w3 = __uint_as_float(q3 & 0xFFFF0000u);
                __hip_bfloat162 h0 = ((const __hip_bfloat162*)(Xh + (size_t)s0 * D))[ln];
                __hip_bfloat162 h1 = ((const __hip_bfloat162*)(Xh + (size_t)s1 * D))[ln];
                __hip_bfloat162 h2 = ((const __hip_bfloat162*)(Xh + (size_t)s2 * D))[ln];
                __hip_bfloat162 h3 = ((const __hip_bfloat162*)(Xh + (size_t)s3 * D))[ln];
                accx = fmaf(w0, __bfloat162float(h0.x), accx);
                accy = fmaf(w0, __bfloat162float(h0.y), accy);
                accx = fmaf(w1, __bfloat162float(h1.x), accx);
                accy = fmaf(w1, __bfloat162float(h1.y), accy);
                accx = fmaf(w2, __bfloat162float(h2.x), accx);
                accy = fmaf(w2, __bfloat162float(h2.y), accy);
                accx = fmaf(w3, __bfloat162float(h3.x), accx);
                accy = fmaf(w3, __bfloat162float(h3.y), accy);
            }
            for (; j < icnt; ++j) {
                unsigned int q0 = stage[ibeg + j];
                int s0 = (int)(q0 & 0xFFFFu);
                float w0 = __uint_as_float(q0 & 0xFFFF0000u);
                __hip_bfloat162 h0 = ((const __hip_bfloat162*)(Xh + (size_t)s0 * D))[ln];
                accx = fmaf(w0, __bfloat162float(h0.x), accx);
                accy = fmaf(w0, __bfloat162float(h0.y), accy);
            }
            float invd = 1.0f / fmaxf((float)icnt, 1.0f);
            ((float2*)(out + (size_t)(nb0 + i) * D))[ln] =
                make_float2(accx * invd, accy * invd);
        }
    } else {
        // ---- rare overflow path (bucket > CAP records): ballot scan ----
        for (int k = tid; k < count; k += 1024)
            atomicAdd(&nhist[(temp[rbeg + k] >> 16) & 127u], 1);
        __syncthreads();
        for (int i = wv; i < nv; i += 16) {
            float4 cd = cdl[i];
            float accx = 0.0f, accy = 0.0f;
            for (int base = 0; base < count; base += 64) {
                int k = base + ln;
                unsigned int rec = (k < count) ? temp[rbeg + k] : 0u;
                bool ok = (k < count) && ((int)((rec >> 16) & 127u) == i);
                unsigned long long mask = __ballot(ok);
                while (mask) {
                    int bpos = __ffsll((long long)mask) - 1;
                    mask &= mask - 1;
                    unsigned int rr = __shfl(rec, bpos);
                    int s0 = (int)(rr & 0xFFFFu);
                    float4 cs = coeff[s0];
                    float w = cs.x * cd.x + cs.y * cd.y + cs.z * cd.z;
                    __hip_bfloat162 h0 = ((const __hip_bfloat162*)(Xh + (size_t)s0 * D))[ln];
                    accx = fmaf(w, __bfloat162float(h0.x), accx);
                    accy = fmaf(w, __bfloat162float(h0.y), accy);
                }
            }
            float invd = 1.0f / fmaxf((float)nhist[i], 1.0f);
            ((float2*)(out + (size_t)(nb0 + i) * D))[ln] =
                make_float2(accx * invd, accy * invd);
        }
    }
}

// ---------------------------------------------------------------------------
// Minimal-workspace / large-n fallback: float-atomic scatter
// ---------------------------------------------------------------------------
__global__ void lg_deg_kernel(const int* __restrict__ dst, int* __restrict__ deg, int E) {
    int e = (int)(blockIdx.x * (size_t)blockDim.x + threadIdx.x);
    if (e < E) atomicAdd(&deg[dst[e]], 1);
}

__global__ void lg_scatter_kernel(const float* __restrict__ X,
                                  const float4* __restrict__ coeff,
                                  const int* __restrict__ src, const int* __restrict__ dst,
                                  float* __restrict__ out, int E) {
    int e = (int)((blockIdx.x * (size_t)blockDim.x + threadIdx.x) >> 6);
    int lane = threadIdx.x & 63;
    if (e >= E) return;
    int s = src[e], d = dst[e];
    float4 cs = coeff[s], cd = coeff[d];
    float se = cs.x * cd.x + cs.y * cd.y + cs.z * cd.z;
    float2 x = ((const float2*)(X + (size_t)s * D))[lane];
    atomicAdd(&out[(size_t)d * D + lane * 2 + 0], se * x.x);
    atomicAdd(&out[(size_t)d * D + lane * 2 + 1], se * x.y);
}

__global__ void lg_scale_kernel(float* __restrict__ out, const int* __restrict__ deg, int n) {
    int node = (int)((blockIdx.x * (size_t)blockDim.x + threadIdx.x) >> 6);
    int lane = threadIdx.x & 63;
    if (node >= n) return;
    float invd = 1.0f / fmaxf((float)deg[node], 1.0f);
    float2* p = (float2*)(out + (size_t)node * D);
    float2 v = p[lane];
    p[lane] = make_float2(v.x * invd, v.y * invd);
}

extern "C" void kernel_launch(void* const* d_in, const int* in_sizes, int n_in,
                              void* d_out, int out_size, void* d_ws, size_t ws_size,
                              hipStream_t stream) {
    const float* X   = (const float*)d_in[0];
    const int*   src = (const int*)d_in[1];
    const int*   dst = (const int*)d_in[2];
    const float* W   = (const float*)d_in[3];
    const float* b   = (const float*)d_in[4];
    float* out = (float*)d_out;
    int n = in_sizes[0] / D;
    int E = in_sizes[1];

    int nbuck = (n + BN - 1) / BN;      // dst buckets

    char* ws = (char*)d_ws;
    size_t p = 0;
    auto alloc = [&](size_t bytes) -> void* {
        void* r = ws + p;
        p = (p + bytes + 255) & ~(size_t)255;
        return r;
    };
    float4* coeff  = (float4*)alloc((size_t)n * sizeof(float4));
    int*    bcnt   = (int*)alloc((size_t)nbuck * sizeof(int));
    int*    boff   = (int*)alloc((size_t)(nbuck + 1) * sizeof(int));
    int*    cursor = (int*)alloc((size_t)nbuck * sizeof(int));
    unsigned int* temp = (unsigned int*)alloc((size_t)E * sizeof(unsigned int));
    __hip_bfloat16* Xh = (__hip_bfloat16*)alloc((size_t)n * D * sizeof(__hip_bfloat16));
    size_t p_full = p;
    int*    deg    = (int*)alloc((size_t)n * sizeof(int));   // fallback only

    int node_blocks = (n + 3) / 4;      // 4 waves (nodes) per 256-thread block
    int edge_blocks = (E + 255) / 256;
    int chunk_blocks = (E + CH - 1) / CH;

    bool fast_ok = (n <= 65536) && (nbuck <= 512) && (p_full <= ws_size);
    if (fast_ok) {
        // no memsets: bcnt zeroed by coeff block 0 (stream-ordered before bcount)
        lg_coeff_kernel<<<node_blocks, 256, 0, stream>>>(X, W, b, coeff, Xh,
                                                         bcnt, nbuck, n);
        lg_bcount_kernel<<<chunk_blocks, 1024, 0, stream>>>(dst, bcnt, E, nbuck);
        lg_bscan_kernel<<<1, 512, 0, stream>>>(bcnt, boff, cursor, nbuck, E);
        lg_bin_kernel<<<chunk_blocks, BIN_T, 0, stream>>>(src, dst, cursor, temp, E, nbuck);
        lg_sortagg_kernel<<<nbuck, 1024, 0, stream>>>(Xh, coeff, temp, boff, out, n);
    } else {
        // fallback: coeff + deg; atomic scatter
        hipMemsetAsync(deg, 0, (size_t)n * sizeof(int), stream);
        hipMemsetAsync(out, 0, (size_t)n * D * sizeof(float), stream);
        lg_coeff_kernel<<<node_blocks, 256, 0, stream>>>(X, W, b, coeff, nullptr,
                                                         nullptr, 0, n);
        lg_deg_kernel<<<edge_blocks, 256, 0, stream>>>(dst, deg, E);
        lg_scatter_kernel<<<(E + 3) / 4, 256, 0, stream>>>(X, coeff, src, dst, out, E);
        lg_scale_kernel<<<node_blocks, 256, 0, stream>>>(out, deg, n);
    }
}